// Round 4
// baseline (6794.494 us; speedup 1.0000x reference)
//
#include <hip/hip_runtime.h>
#include <hip/hip_bf16.h>
#include <cstdint>
#include <cstddef>

#define NTOK 50257
#define NPADT 50304     // 393*128, padded row count of transposed W
#define HA   2048
#define HD   512
#define MR   4096       // T*B

typedef unsigned short u16;
typedef __attribute__((ext_vector_type(8))) short bf16x8;
typedef __attribute__((ext_vector_type(4))) float f32x4;

// ---------------- d_out offsets (floats) ----------------
static const size_t OFS_H0F  = (size_t)MR * NTOK;
static const size_t OFS_H1F  = OFS_H0F + 64 * 512;
static const size_t OFS_LOSS = OFS_H1F + 64 * 512;
static const size_t OFS_IN0  = OFS_LOSS + 1;
static const size_t OFS_IN1  = OFS_IN0 + (size_t)64 * 512 * 4;

// ---------------- ws layout A: MFMA path (~139 MiB, floats) ----------------
static const size_t F_WHIT  = 0;                              // u16[NPADT*512] = 12,877,824 floats
static const size_t F_WLOT  = F_WHIT + (size_t)NPADT * 512 / 2;
static const size_t F_X0    = F_WLOT + (size_t)NPADT * 512 / 2;   // 4096*2048 floats
static const size_t F_AHI   = F_X0;                           // alias (X0 dead after scan), u16[2M]
static const size_t F_ALO   = F_X0 + (size_t)MR * HD / 2;
static const size_t F_H1ALL = F_X0 + (size_t)MR * HA;
static const size_t F_H0    = F_H1ALL + (size_t)MR * HD;
static const size_t F_H1    = F_H0 + 2 * 64 * 512;
static const size_t F_BAR   = F_H1 + 2 * 64 * 512;            // 1024 floats
static const size_t F_LOSSA = F_BAR + 1024;
static const size_t F_END   = F_LOSSA + 16;

// ---------------- ws layout B: fp32 fallback (~42.5 MiB, floats) ----------------
static const size_t S_X0    = 0;
static const size_t S_H1ALL = S_X0 + (size_t)MR * HA;
static const size_t S_H0    = S_H1ALL + (size_t)MR * HD;
static const size_t S_H1    = S_H0 + 2 * 64 * 512;
static const size_t S_BAR   = S_H1 + 2 * 64 * 512;
static const size_t S_LOSSA = S_BAR + 1024;
static const size_t S_END   = S_LOSSA + 16;

// ---------------- bf16 split helpers ----------------
__device__ __forceinline__ u16 f2bf(float v) {
  __hip_bfloat16 b = __float2bfloat16(v);
  return *reinterpret_cast<u16*>(&b);
}
__device__ __forceinline__ float bf2f(u16 u) {
  __hip_bfloat16 b;
  *reinterpret_cast<u16*>(&b) = u;
  return __bfloat162float(b);
}

// ======================================================================
// two-level device-scope grid barrier (monotone counters, no reset)
// 8 groups x 32 blocks; grp counters on separate 256B-spaced lines.
// ======================================================================
__device__ __forceinline__ void gridbar2(unsigned* grp, unsigned* sup, int g, unsigned gen) {
  __threadfence();
  __syncthreads();
  if (threadIdx.x == 0) {
    unsigned old = __hip_atomic_fetch_add(&grp[g * 64], 1u, __ATOMIC_ACQ_REL, __HIP_MEMORY_SCOPE_AGENT);
    if (old + 1u == 32u * gen)
      __hip_atomic_fetch_add(sup, 1u, __ATOMIC_ACQ_REL, __HIP_MEMORY_SCOPE_AGENT);
    while (__hip_atomic_load(sup, __ATOMIC_ACQUIRE, __HIP_MEMORY_SCOPE_AGENT) < 8u * gen) {
      __builtin_amdgcn_s_sleep(1);
    }
  }
  __syncthreads();
  __threadfence();
}

// ======================================================================
// 1) X0[r][j] = encoder_w[x[r]] @ Wih0 + bih0 + bhh0   (M=4096,N=2048,K=512)
// ======================================================================
__global__ __launch_bounds__(256) void k_x0(const int* __restrict__ x,
                                            const float* __restrict__ enc,
                                            const float* __restrict__ Wih0,
                                            const float* __restrict__ bih0,
                                            const float* __restrict__ bhh0,
                                            float* __restrict__ X0) {
  __shared__ __align__(16) float As[16][64];
  __shared__ __align__(16) float Bs[16][64];
  const int tid = threadIdx.x;
  const int bx = blockIdx.x;
  const int by = blockIdx.y;
  const int am = tid >> 2, ak = (tid & 3) << 2;
  const int bk = tid >> 4, bc = (tid & 15) << 2;
  const int ty = tid >> 4, tx = tid & 15;
  const int tok = x[by * 64 + am];
  const float* arp = enc + (size_t)tok * 512;
  float acc[4][4] = {{0.f}};
  for (int kb = 0; kb < 512; kb += 16) {
    float4 av = *(const float4*)(arp + kb + ak);
    float4 bv = *(const float4*)(Wih0 + (size_t)(kb + bk) * HA + bx * 64 + bc);
    __syncthreads();
    As[ak + 0][am] = av.x; As[ak + 1][am] = av.y;
    As[ak + 2][am] = av.z; As[ak + 3][am] = av.w;
    *(float4*)&Bs[bk][bc] = bv;
    __syncthreads();
#pragma unroll
    for (int k = 0; k < 16; ++k) {
      float4 a = *(const float4*)&As[k][ty << 2];
      float4 b = *(const float4*)&Bs[k][tx << 2];
      acc[0][0] += a.x * b.x; acc[0][1] += a.x * b.y; acc[0][2] += a.x * b.z; acc[0][3] += a.x * b.w;
      acc[1][0] += a.y * b.x; acc[1][1] += a.y * b.y; acc[1][2] += a.y * b.z; acc[1][3] += a.y * b.w;
      acc[2][0] += a.z * b.x; acc[2][1] += a.z * b.y; acc[2][2] += a.z * b.z; acc[2][3] += a.z * b.w;
      acc[3][0] += a.w * b.x; acc[3][1] += a.w * b.y; acc[3][2] += a.w * b.z; acc[3][3] += a.w * b.w;
    }
  }
  const int row0 = by * 64 + (ty << 2);
  const int col0 = bx * 64 + (tx << 2);
  float4 bi = *(const float4*)(bih0 + col0);
  float4 bh = *(const float4*)(bhh0 + col0);
#pragma unroll
  for (int i = 0; i < 4; ++i) {
    float4 v;
    v.x = acc[i][0] + bi.x + bh.x;
    v.y = acc[i][1] + bi.y + bh.y;
    v.z = acc[i][2] + bi.z + bh.z;
    v.w = acc[i][3] + bi.w + bh.w;
    *(float4*)(X0 + (size_t)(row0 + i) * HA + col0) = v;
  }
}

// ======================================================================
// per-neuron MLP: A=4 -> 16 -> 16 -> 1
// ======================================================================
__device__ __forceinline__ float mlp4(float g0, float g1, float g2, float g3, int c,
                                      const float* sW1, const float* sb1,
                                      const float* sW2, const float* sb2,
                                      const float* sW3, const float* sb3) {
  float h1v[16];
  const float* w1c = sW1 + c * 64;
  const float* b1c = sb1 + c * 16;
#pragma unroll
  for (int i = 0; i < 16; ++i) {
    float v = b1c[i] + g0 * w1c[i] + g1 * w1c[16 + i] + g2 * w1c[32 + i] + g3 * w1c[48 + i];
    h1v[i] = fmaxf(v, 0.f);
  }
  const float* w2c = sW2 + c * 256;
  const float* b2c = sb2 + c * 16;
  float o = sb3[c];
  const float* w3c = sW3 + c * 16;
#pragma unroll
  for (int j = 0; j < 16; ++j) {
    float v = b2c[j];
#pragma unroll
    for (int i = 0; i < 16; ++i) v += h1v[i] * w2c[i * 16 + j];
    o += fmaxf(v, 0.f) * w3c[j];
  }
  return o;
}

// ======================================================================
// 2) persistent scan kernel: 256 WGs x 256 threads, weights LDS-resident,
//    software-pipelined A(s) || B(s-1), one 2-level barrier per superstep.
// ======================================================================
#define DOT256(HR, WPP, A0, A1, A2, A3)                                    \
  for (int k = 0; k < 256; k += 4) {                                       \
    float4 h4 = *(const float4*)((HR) + k);                                \
    const float* wk = (WPP) + k * 16;                                      \
    float4 u0 = *(const float4*)(wk);                                      \
    float4 u1 = *(const float4*)(wk + 16);                                 \
    float4 u2 = *(const float4*)(wk + 32);                                 \
    float4 u3 = *(const float4*)(wk + 48);                                 \
    A0 += h4.x * u0.x + h4.y * u1.x + h4.z * u2.x + h4.w * u3.x;           \
    A1 += h4.x * u0.y + h4.y * u1.y + h4.z * u2.y + h4.w * u3.y;           \
    A2 += h4.x * u0.z + h4.y * u1.z + h4.z * u2.z + h4.w * u3.z;           \
    A3 += h4.x * u0.w + h4.y * u1.w + h4.z * u2.w + h4.w * u3.w;           \
  }

__global__ __launch_bounds__(256) void k_scan(
    const float* __restrict__ X0, const float* __restrict__ Whh0,
    const float* __restrict__ Wih1, const float* __restrict__ Whh1,
    const float* __restrict__ bih1, const float* __restrict__ bhh1,
    const float* __restrict__ W1, const float* __restrict__ b1,
    const float* __restrict__ W2, const float* __restrict__ b2,
    const float* __restrict__ W3, const float* __restrict__ b3,
    float* __restrict__ h0buf, float* __restrict__ h1buf,
    float* __restrict__ H1all, float* __restrict__ dout,
    unsigned* __restrict__ grpcnt, unsigned* __restrict__ supcnt) {
  __shared__ __align__(16) float sW0[512 * 16];
  __shared__ __align__(16) float sWi1[512 * 16];
  __shared__ __align__(16) float sWh1[512 * 16];
  __shared__ float sMLP[1476];
  const int tid = threadIdx.x;
  const int wx = blockIdx.x & 127;
  const int wy = blockIdx.x >> 7;
  const int g  = blockIdx.x & 7;

#pragma unroll
  for (int ii = 0; ii < 8; ++ii) {
    int flat = (ii * 256 + tid) * 4;
    size_t src = (size_t)(flat >> 4) * HA + (wx << 4) + (flat & 15);
    *(float4*)&sW0[flat]  = *(const float4*)(Whh0 + src);
    *(float4*)&sWi1[flat] = *(const float4*)(Wih1 + src);
    *(float4*)&sWh1[flat] = *(const float4*)(Whh1 + src);
  }
  for (int i = tid; i < 1476; i += 256) {
    float v;
    if (i < 256)       v = W1[i];
    else if (i < 320)  v = b1[i - 256];
    else if (i < 1344) v = W2[i - 320];
    else if (i < 1408) v = b2[i - 1344];
    else if (i < 1472) v = W3[i - 1408];
    else               v = b3[i - 1472];
    sMLP[i] = v;
  }
  const float* sW1m = sMLP;
  const float* sb1m = sMLP + 256;
  const float* sW2m = sMLP + 320;
  const float* sb2m = sMLP + 1344;
  const float* sW3m = sMLP + 1408;
  const float* sb3m = sMLP + 1472;
  __syncthreads();

  const int r  = (wy << 5) + (tid >> 3);
  const int nl = (tid & 7) >> 1;
  const int kh = tid & 1;
  const int n  = (wx << 2) + nl;
  const int col = n << 2;
  const int c  = n >> 7;
  const int k0 = kh << 8;
  const int wofs = k0 * 16 + (nl << 2);

  float bb0 = 0.f, bb1 = 0.f, bb2 = 0.f, bb3 = 0.f;
  if (kh == 0) {
    bb0 = bih1[col + 0] + bhh1[col + 0];
    bb1 = bih1[col + 1] + bhh1[col + 1];
    bb2 = bih1[col + 2] + bhh1[col + 2];
    bb3 = bih1[col + 3] + bhh1[col + 3];
  }

  unsigned gen = 0;
  for (int s = 0; s <= 64; ++s) {
    if (s < 64) {
      const float* h0c = h0buf + (s & 1) * 32768;
      float*       h0n = h0buf + ((s + 1) & 1) * 32768;
      float a0, a1, a2, a3;
      if (kh == 0) {
        float4 xv = *(const float4*)(X0 + (size_t)((s << 6) + r) * HA + col);
        a0 = xv.x; a1 = xv.y; a2 = xv.z; a3 = xv.w;
      } else { a0 = a1 = a2 = a3 = 0.f; }
      {
        const float* hr = h0c + r * HD + k0;
        DOT256(hr, sW0 + wofs, a0, a1, a2, a3);
      }
      a0 += __shfl_xor(a0, 1);
      a1 += __shfl_xor(a1, 1);
      a2 += __shfl_xor(a2, 1);
      a3 += __shfl_xor(a3, 1);
      if (kh == 0) {
        if (s == 63) {
          size_t o = OFS_IN0 + (((size_t)r * HD + n) << 2);
          dout[o + 0] = a0; dout[o + 1] = a1; dout[o + 2] = a2; dout[o + 3] = a3;
        }
        float o = mlp4(a0, a1, a2, a3, c, sW1m, sb1m, sW2m, sb2m, sW3m, sb3m);
        h0n[r * HD + n] = o;
        if (s == 63) dout[OFS_H0F + r * HD + n] = o;
      }
    }

    if (s >= 1) {
      const int tb = s - 1;
      const float* h0in = h0buf + (s & 1) * 32768;
      const float* h1c  = h1buf + (tb & 1) * 32768;
      float*       h1n  = h1buf + ((tb + 1) & 1) * 32768;
      float p0, p1, p2, p3;
      if (kh == 0) { p0 = bb0; p1 = bb1; p2 = bb2; p3 = bb3; }
      else         { p0 = p1 = p2 = p3 = 0.f; }
      {
        const float* hr = h0in + r * HD + k0;
        DOT256(hr, sWi1 + wofs, p0, p1, p2, p3);
      }
      {
        const float* hr = h1c + r * HD + k0;
        DOT256(hr, sWh1 + wofs, p0, p1, p2, p3);
      }
      p0 += __shfl_xor(p0, 1);
      p1 += __shfl_xor(p1, 1);
      p2 += __shfl_xor(p2, 1);
      p3 += __shfl_xor(p3, 1);
      if (kh == 0) {
        if (tb == 63) {
          size_t o = OFS_IN1 + (((size_t)r * HD + n) << 2);
          dout[o + 0] = p0; dout[o + 1] = p1; dout[o + 2] = p2; dout[o + 3] = p3;
        }
        float o = mlp4(p0, p1, p2, p3, c, sW1m, sb1m, sW2m, sb2m, sW3m, sb3m);
        h1n[r * HD + n] = o;
        H1all[(size_t)((tb << 6) + r) * HD + n] = o;
        if (tb == 63) dout[OFS_H1F + r * HD + n] = o;
      }
    }

    if (s < 64) {
      ++gen;
      gridbar2(grpcnt, supcnt, g, gen);
    }
  }
}

// ======================================================================
// 3a) split H1all fp32 -> Ahi/Alo bf16 (row-major [4096][512])
// ======================================================================
__global__ __launch_bounds__(256) void k_split_h(const float* __restrict__ src,
                                                 u16* __restrict__ ahi,
                                                 u16* __restrict__ alo) {
  int idx = blockIdx.x * 256 + threadIdx.x;   // exact: 8192*256 = 2M
  float v = src[idx];
  u16 hi = f2bf(v);
  u16 lo = f2bf(v - bf2f(hi));
  ahi[idx] = hi;
  alo[idx] = lo;
}

// ======================================================================
// 3b) split+transpose dec_w [512][50257] fp32 -> WhiT/WloT [50304][512] bf16
// ======================================================================
__global__ __launch_bounds__(256) void k_split_wT(const float* __restrict__ w,
                                                  u16* __restrict__ whiT,
                                                  u16* __restrict__ wloT) {
  __shared__ float tile[32][33];
  const int tid = threadIdx.x;
  const int tx = tid & 31, ty = tid >> 5;     // 32 x 8
  const int n0 = blockIdx.x * 32;             // 1572 blocks -> 50304
  const int k0 = blockIdx.y * 32;             // 16 blocks -> 512
#pragma unroll
  for (int i = 0; i < 4; ++i) {
    int k = k0 + ty * 4 + i;
    int nn = n0 + tx;
    tile[ty * 4 + i][tx] = (nn < NTOK) ? w[(size_t)k * NTOK + nn] : 0.f;
  }
  __syncthreads();
#pragma unroll
  for (int i = 0; i < 4; ++i) {
    int nn = n0 + ty * 4 + i;
    int k = k0 + tx;
    float v = tile[tx][ty * 4 + i];
    u16 hi = f2bf(v);
    u16 lo = f2bf(v - bf2f(hi));
    whiT[(size_t)nn * 512 + k] = hi;
    wloT[(size_t)nn * 512 + k] = lo;
  }
}

// ======================================================================
// 3c) MFMA decoder: C[4096][50257] = H @ W + b via split-bf16 (hh+hl+lh).
//     Block 256 = 4 waves (2x2), block tile 128x128, wave tile 64x64.
//     All fragments are contiguous 16B global loads (A L2-resident,
//     W-T L3-resident). Verified C/D layout: col=lane&15, row=(lane>>4)*4+q.
// ======================================================================
__global__ __launch_bounds__(256) void k_dec_mfma(const u16* __restrict__ Ahi,
                                                  const u16* __restrict__ Alo,
                                                  const u16* __restrict__ WhiT,
                                                  const u16* __restrict__ WloT,
                                                  const float* __restrict__ bias,
                                                  float* __restrict__ C) {
  const int tid  = threadIdx.x;
  const int wid  = tid >> 6;
  const int lane = tid & 63;
  const int l15  = lane & 15;
  const int g    = lane >> 4;
  const int mbase = blockIdx.y * 128 + (wid >> 1) * 64;
  const int nbase = blockIdx.x * 128 + (wid & 1) * 64;

  f32x4 acc[4][4] = {};
  for (int k0 = 0; k0 < 512; k0 += 32) {
    bf16x8 ah[4], al[4], bh[4], bl[4];
#pragma unroll
    for (int mf = 0; mf < 4; ++mf) {
      size_t off = (size_t)(mbase + mf * 16 + l15) * 512 + k0 + 8 * g;
      ah[mf] = *(const bf16x8*)(Ahi + off);
      al[mf] = *(const bf16x8*)(Alo + off);
    }
#pragma unroll
    for (int nf = 0; nf < 4; ++nf) {
      size_t off = (size_t)(nbase + nf * 16 + l15) * 512 + k0 + 8 * g;
      bh[nf] = *(const bf16x8*)(WhiT + off);
      bl[nf] = *(const bf16x8*)(WloT + off);
    }
#pragma unroll
    for (int mf = 0; mf < 4; ++mf)
#pragma unroll
      for (int nf = 0; nf < 4; ++nf) {
        acc[mf][nf] = __builtin_amdgcn_mfma_f32_16x16x32_bf16(ah[mf], bh[nf], acc[mf][nf], 0, 0, 0);
        acc[mf][nf] = __builtin_amdgcn_mfma_f32_16x16x32_bf16(ah[mf], bl[nf], acc[mf][nf], 0, 0, 0);
        acc[mf][nf] = __builtin_amdgcn_mfma_f32_16x16x32_bf16(al[mf], bh[nf], acc[mf][nf], 0, 0, 0);
      }
  }

#pragma unroll
  for (int nf = 0; nf < 4; ++nf) {
    const int col = nbase + nf * 16 + l15;
    if (col < NTOK) {
      const float b = bias[col];
#pragma unroll
      for (int mf = 0; mf < 4; ++mf) {
        const int row = mbase + mf * 16 + g * 4;
#pragma unroll
        for (int q = 0; q < 4; ++q)
          C[(size_t)(row + q) * NTOK + col] = acc[mf][nf][q] + b;
      }
    }
  }
}

// ======================================================================
// 3d) fp32 decoder fallback (used only if ws_size too small for MFMA path)
// ======================================================================
__global__ __launch_bounds__(256) void k_dec(const float* __restrict__ A,
                                             const float* __restrict__ Bw,
                                             const float* __restrict__ bias,
                                             float* __restrict__ C) {
  __shared__ __align__(16) float As[8][128];
  __shared__ __align__(16) float Bs[8][128];
  const int tid = threadIdx.x;
  const int bx = blockIdx.x;
  const int by = blockIdx.y;
  const int am = tid >> 1;
  const int ak = (tid & 1) << 2;
  const int bk = tid >> 5;
  const int bc = (tid & 31) << 2;
  const int ty = tid >> 4;
  const int tx = tid & 15;
  const float* arp = A + (size_t)(by * 128 + am) * 512;
  const int    bcol = bx * 128 + bc;
  const float* brp = Bw + (size_t)bk * NTOK + bcol;
  float acc[8][8] = {{0.f}};
  for (int kb = 0; kb < 512; kb += 8) {
    float4 av = *(const float4*)(arp + kb + ak);
    const float* bp = brp + (size_t)kb * NTOK;
    float b0 = (bcol + 0 < NTOK) ? bp[0] : 0.f;
    float b1 = (bcol + 1 < NTOK) ? bp[1] : 0.f;
    float b2 = (bcol + 2 < NTOK) ? bp[2] : 0.f;
    float b3 = (bcol + 3 < NTOK) ? bp[3] : 0.f;
    __syncthreads();
    As[ak + 0][am] = av.x; As[ak + 1][am] = av.y;
    As[ak + 2][am] = av.z; As[ak + 3][am] = av.w;
    Bs[bk][bc + 0] = b0; Bs[bk][bc + 1] = b1;
    Bs[bk][bc + 2] = b2; Bs[bk][bc + 3] = b3;
    __syncthreads();
#pragma unroll
    for (int k = 0; k < 8; ++k) {
      float4 a0 = *(const float4*)&As[k][ty << 3];
      float4 a1 = *(const float4*)&As[k][(ty << 3) + 4];
      float4 q0 = *(const float4*)&Bs[k][tx << 3];
      float4 q1 = *(const float4*)&Bs[k][(tx << 3) + 4];
      float ar[8] = {a0.x, a0.y, a0.z, a0.w, a1.x, a1.y, a1.z, a1.w};
      float br[8] = {q0.x, q0.y, q0.z, q0.w, q1.x, q1.y, q1.z, q1.w};
#pragma unroll
      for (int i = 0; i < 8; ++i)
#pragma unroll
        for (int j = 0; j < 8; ++j)
          acc[i][j] += ar[i] * br[j];
    }
  }
  const int row0 = by * 128 + (ty << 3);
  const int col0 = bx * 128 + (tx << 3);
  if (col0 + 8 <= NTOK) {
    float4 bi0 = *(const float4*)(bias + col0);
    float4 bi1 = *(const float4*)(bias + col0 + 4);
#pragma unroll
    for (int i = 0; i < 8; ++i) {
      float* cp = C + (size_t)(row0 + i) * NTOK + col0;
      cp[0] = acc[i][0] + bi0.x; cp[1] = acc[i][1] + bi0.y;
      cp[2] = acc[i][2] + bi0.z; cp[3] = acc[i][3] + bi0.w;
      cp[4] = acc[i][4] + bi1.x; cp[5] = acc[i][5] + bi1.y;
      cp[6] = acc[i][6] + bi1.z; cp[7] = acc[i][7] + bi1.w;
    }
  } else {
#pragma unroll
    for (int i = 0; i < 8; ++i)
#pragma unroll
      for (int j = 0; j < 8; ++j) {
        int cc = col0 + j;
        if (cc < NTOK) C[(size_t)(row0 + i) * NTOK + cc] = acc[i][j] + bias[cc];
      }
  }
}

// ======================================================================
// 4) loss: one WG per row, single-pass online max/sum, atomic accumulate
// ======================================================================
__global__ __launch_bounds__(256) void k_loss(const float* __restrict__ logits,
                                              const int* __restrict__ labels,
                                              float* __restrict__ acc) {
  const int row = blockIdx.x;
  const int tid = threadIdx.x;
  const float* rp = logits + (size_t)row * NTOK;
  float m = -3.4e38f, s = 0.f;
  auto upd = [&m, &s](float v) {
    if (v > m) { s *= __expf(m - v); m = v; }
    s += __expf(v - m);
  };
  const int head = (4 - (int)((((uintptr_t)rp) >> 2) & 3)) & 3;
  if (tid < head) upd(rp[tid]);
  const int nv = (NTOK - head) >> 2;
  const float4* vp = (const float4*)(rp + head);
  for (int i = tid; i < nv; i += 256) {
    float4 v = vp[i];
    upd(v.x); upd(v.y); upd(v.z); upd(v.w);
  }
  for (int j = head + nv * 4 + tid; j < NTOK; j += 256) upd(rp[j]);

  __shared__ float rm[256], rs[256];
  rm[tid] = m; rs[tid] = s;
  __syncthreads();
  for (int off = 128; off > 0; off >>= 1) {
    if (tid < off) {
      float m2 = rm[tid + off], s2 = rs[tid + off];
      float M = fmaxf(rm[tid], m2);
      rs[tid] = rs[tid] * __expf(rm[tid] - M) + s2 * __expf(m2 - M);
      rm[tid] = M;
    }
    __syncthreads();
  }
  if (tid == 0) {
    float lse = rm[0] + logf(rs[0]);
    float tv = rp[labels[row]];
    atomicAdd(acc, lse - tv);
  }
}

__global__ void k_fin(const float* __restrict__ acc, float* __restrict__ out) {
  out[0] = acc[0] * (1.f / 4096.f);
}

// ======================================================================
extern "C" void kernel_launch(void* const* d_in, const int* in_sizes, int n_in,
                              void* d_out, int out_size, void* d_ws, size_t ws_size,
                              hipStream_t stream) {
  const int*   x      = (const int*)d_in[0];
  const int*   labels = (const int*)d_in[1];
  const float* enc    = (const float*)d_in[2];
  const float* Wih0   = (const float*)d_in[3];
  const float* bih0   = (const float*)d_in[4];
  const float* Whh0   = (const float*)d_in[5];
  const float* bhh0   = (const float*)d_in[6];
  const float* Wih1   = (const float*)d_in[7];
  const float* bih1   = (const float*)d_in[8];
  const float* Whh1   = (const float*)d_in[9];
  const float* bhh1   = (const float*)d_in[10];
  const float* W1     = (const float*)d_in[11];
  const float* b1     = (const float*)d_in[12];
  const float* W2     = (const float*)d_in[13];
  const float* b2     = (const float*)d_in[14];
  const float* W3     = (const float*)d_in[15];
  const float* b3     = (const float*)d_in[16];
  const float* dec_w  = (const float*)d_in[17];
  const float* dec_b  = (const float*)d_in[18];

  float* out = (float*)d_out;
  float* wsf = (float*)d_ws;
  const bool mfma_ok = ws_size >= F_END * sizeof(float);

  // select ws layout (host-constant branch -> graph-capture safe)
  const size_t oX0 = mfma_ok ? F_X0 : S_X0;
  const size_t oH1 = mfma_ok ? F_H1ALL : S_H1ALL;
  const size_t oH0b = mfma_ok ? F_H0 : S_H0;
  const size_t oH1b = mfma_ok ? F_H1 : S_H1;
  const size_t oBar = mfma_ok ? F_BAR : S_BAR;
  const size_t oLoss = mfma_ok ? F_LOSSA : S_LOSSA;
  const size_t oEnd = mfma_ok ? F_END : S_END;

  float* X0     = wsf + oX0;
  float* H1all  = wsf + oH1;
  float* h0buf  = wsf + oH0b;
  float* h1buf  = wsf + oH1b;
  unsigned* grpcnt = (unsigned*)(wsf + oBar);
  unsigned* supcnt = (unsigned*)(wsf + oBar) + 512;
  float* lossa  = wsf + oLoss;

  // zero h-state, barrier counters, loss accumulator (ws is poisoned 0xAA)
  hipMemsetAsync(wsf + oH0b, 0, (oEnd - oH0b) * sizeof(float), stream);

  k_x0<<<dim3(32, 64), 256, 0, stream>>>(x, enc, Wih0, bih0, bhh0, X0);
  k_scan<<<256, 256, 0, stream>>>(X0, Whh0, Wih1, Whh1, bih1, bhh1,
                                  W1, b1, W2, b2, W3, b3,
                                  h0buf, h1buf, H1all, out, grpcnt, supcnt);

  if (mfma_ok) {
    u16* WhiT = (u16*)(wsf + F_WHIT);
    u16* WloT = (u16*)(wsf + F_WLOT);
    u16* Ahi  = (u16*)(wsf + F_AHI);
    u16* Alo  = (u16*)(wsf + F_ALO);
    k_split_wT<<<dim3(1572, 16), 256, 0, stream>>>(dec_w, WhiT, WloT);
    k_split_h<<<8192, 256, 0, stream>>>(H1all, Ahi, Alo);
    k_dec_mfma<<<dim3(393, 32), 256, 0, stream>>>(Ahi, Alo, WhiT, WloT, dec_b, out);
  } else {
    k_dec<<<dim3(393, 32), 256, 0, stream>>>(H1all, dec_w, dec_b, out);
  }

  k_loss<<<4096, 256, 0, stream>>>(out, labels, lossa);
  k_fin<<<1, 1, 0, stream>>>(lossa, out + OFS_LOSS);
}